// Round 1
// baseline (622.592 us; speedup 1.0000x reference)
//
#include <hip/hip_runtime.h>
#include <math.h>

// ---------------------------------------------------------------------------
// dual matvec: one block per row. Computes
//   h_out[row] = f(dot(W[row], v) + b[row])
//   t_out[row] = f'(...) * dot(W[row], t)        (tangent / JVP)
// f = sigmoid if SIG, else identity (t_out = raw dot).
// Weight row read ONCE serves both dots -> memory-bound at weight traffic.
// ---------------------------------------------------------------------------
template <bool SIG>
__global__ __launch_bounds__(256) void dual_matvec(
    const float* __restrict__ W, const float* __restrict__ b,
    const float* __restrict__ v, const float* __restrict__ t,
    float* __restrict__ h_out, float* __restrict__ t_out, int ncols)
{
    const int row = blockIdx.x;
    const int tid = threadIdx.x;
    const float4* __restrict__ W4 = (const float4*)(W + (size_t)row * ncols);
    const float4* __restrict__ v4 = (const float4*)v;
    const float4* __restrict__ t4 = (const float4*)t;
    const int nvec = ncols >> 2;

    float ah = 0.f, at = 0.f;
    for (int i = tid; i < nvec; i += 256) {
        float4 w = W4[i];
        float4 a = v4[i];
        float4 c = t4[i];
        ah += w.x * a.x + w.y * a.y + w.z * a.z + w.w * a.w;
        at += w.x * c.x + w.y * c.y + w.z * c.z + w.w * c.w;
    }
    // wave64 reduction
    #pragma unroll
    for (int off = 32; off > 0; off >>= 1) {
        ah += __shfl_down(ah, off, 64);
        at += __shfl_down(at, off, 64);
    }
    __shared__ float sh[4], st[4];
    const int wave = tid >> 6;
    if ((tid & 63) == 0) { sh[wave] = ah; st[wave] = at; }
    __syncthreads();
    if (tid == 0) {
        float hsum = sh[0] + sh[1] + sh[2] + sh[3];
        float tsum = st[0] + st[1] + st[2] + st[3];
        hsum += b[row];
        if (SIG) {
            float s = 1.f / (1.f + expf(-hsum));
            h_out[row] = s;
            t_out[row] = s * (1.f - s) * tsum;
        } else {
            h_out[row] = hsum;
            t_out[row] = tsum;
        }
    }
}

// ---------------------------------------------------------------------------
// head kernel: single block, 256 threads. Everything tiny (<= ~65K MACs):
//   z  = W2 @ h2 + b2          dz  = W2 @ t2            (16 x 1024)
//   theta = sindy_library(z)   (984)
//   dzb = E_w @ theta + E_b    (16 x 984)
//   g1 = sigmoid(U0 @ z + c0)  s1 = sig' * (U0 @ dzb)   (1024 x 16)
// Writes z, dz, dzb to out[0..47]; g1, s1 to workspace.
// ---------------------------------------------------------------------------
__global__ __launch_bounds__(256) void head_kernel(
    const float* __restrict__ W2, const float* __restrict__ b2,
    const float* __restrict__ h2, const float* __restrict__ t2,
    const float* __restrict__ Ew, const float* __restrict__ Eb,
    const float* __restrict__ U0, const float* __restrict__ c0,
    float* __restrict__ out,
    float* __restrict__ g1, float* __restrict__ s1)
{
    __shared__ float z_s[16], dz_s[16], dzb_s[16];
    __shared__ float theta[984];
    __shared__ float red_h[256], red_t[256];

    const int tid = threadIdx.x;
    const int r = tid >> 4;   // 0..15
    const int c = tid & 15;   // 0..15

    // ---- z, dz: 16 rows x 1024, 16 threads per row ----
    {
        const float* Wr = W2 + r * 1024;
        float ah = 0.f, at = 0.f;
        for (int idx = c; idx < 1024; idx += 16) {
            float w = Wr[idx];
            ah += w * h2[idx];
            at += w * t2[idx];
        }
        red_h[tid] = ah; red_t[tid] = at;
        __syncthreads();
        if (c == 0) {
            float zs = 0.f, ts = 0.f;
            for (int j = 0; j < 16; j++) { zs += red_h[(r << 4) + j]; ts += red_t[(r << 4) + j]; }
            z_s[r] = zs + b2[r];
            dz_s[r] = ts;
        }
        __syncthreads();
    }

    // ---- sindy library: [1]*16 ++ z ++ quad(136) ++ cub(816) ----
    if (tid < 16) { theta[tid] = 1.0f; theta[16 + tid] = z_s[tid]; }
    for (int t = tid; t < 136; t += 256) {
        int rem = t, i = 0;
        while (rem >= 16 - i) { rem -= 16 - i; i++; }
        int j = i + rem;
        theta[32 + t] = z_s[i] * z_s[j];
    }
    for (int t = tid; t < 816; t += 256) {
        int rem = t, i = 0;
        for (;;) { int cnt = (16 - i) * (17 - i) >> 1; if (rem < cnt) break; rem -= cnt; i++; }
        int j = i;
        while (rem >= 16 - j) { rem -= 16 - j; j++; }
        int k = j + rem;
        theta[168 + t] = z_s[i] * z_s[j] * z_s[k];
    }
    __syncthreads();

    // ---- dzb = E_w @ theta + E_b (16 x 984) ----
    {
        const float* Er = Ew + r * 984;
        float a = 0.f;
        for (int idx = c; idx < 984; idx += 16) a += Er[idx] * theta[idx];
        red_h[tid] = a;
        __syncthreads();
        if (c == 0) {
            float s = 0.f;
            for (int j = 0; j < 16; j++) s += red_h[(r << 4) + j];
            dzb_s[r] = s + Eb[r];
        }
        __syncthreads();
    }

    // ---- outputs z, dz, dzb ----
    if (tid < 16) {
        out[tid]      = z_s[tid];
        out[16 + tid] = dz_s[tid];
        out[32 + tid] = dzb_s[tid];
    }

    // ---- decoder layer 0: g1/s1, 1024 rows x 16 cols ----
    for (int row = tid; row < 1024; row += 256) {
        const float* Ur = U0 + row * 16;
        float ah = 0.f, at = 0.f;
        #pragma unroll
        for (int k = 0; k < 16; k++) {
            float w = Ur[k];
            ah += w * z_s[k];
            at += w * dzb_s[k];
        }
        ah += c0[row];
        float s = 1.f / (1.f + expf(-ah));
        g1[row] = s;
        s1[row] = s * (1.f - s) * at;
    }
}

extern "C" void kernel_launch(void* const* d_in, const int* in_sizes, int n_in,
                              void* d_out, int out_size, void* d_ws, size_t ws_size,
                              hipStream_t stream)
{
    const float* x     = (const float*)d_in[0];
    const float* dx    = (const float*)d_in[1];
    // d_in[2] = ddx: unused by the reference
    const float* we_w0 = (const float*)d_in[3];
    const float* we_b0 = (const float*)d_in[4];
    const float* we_w1 = (const float*)d_in[5];
    const float* we_b1 = (const float*)d_in[6];
    const float* we_w2 = (const float*)d_in[7];
    const float* we_b2 = (const float*)d_in[8];
    const float* wd_w0 = (const float*)d_in[9];
    const float* wd_b0 = (const float*)d_in[10];
    const float* wd_w1 = (const float*)d_in[11];
    const float* wd_b1 = (const float*)d_in[12];
    const float* wd_w2 = (const float*)d_in[13];
    const float* wd_b2 = (const float*)d_in[14];
    const float* E_w   = (const float*)d_in[15];
    const float* E_b   = (const float*)d_in[16];

    float* out = (float*)d_out;   // z[16] dz[16] dzb[16] xb[16384] dxb[16384]
    float* ws  = (float*)d_ws;

    // workspace layout (floats)
    float* h1 = ws;            // 4096
    float* t1 = ws + 4096;     // 4096
    float* h2 = ws + 8192;     // 1024
    float* t2 = ws + 9216;     // 1024
    float* g1 = ws + 10240;    // 1024
    float* s1 = ws + 11264;    // 1024
    float* g2 = ws + 12288;    // 4096
    float* s2 = ws + 16384;    // 4096

    float* xb  = out + 48;
    float* dxb = out + 48 + 16384;

    // encoder layer 0: 4096 x 16384, sigmoid
    dual_matvec<true><<<4096, 256, 0, stream>>>(we_w0, we_b0, x, dx, h1, t1, 16384);
    // encoder layer 1: 1024 x 4096, sigmoid
    dual_matvec<true><<<1024, 256, 0, stream>>>(we_w1, we_b1, h1, t1, h2, t2, 4096);
    // head: z/dz, sindy library, dzb, decoder layer 0
    head_kernel<<<1, 256, 0, stream>>>(we_w2, we_b2, h2, t2, E_w, E_b,
                                       wd_w0, wd_b0, out, g1, s1);
    // decoder layer 1: 4096 x 1024, sigmoid
    dual_matvec<true><<<4096, 256, 0, stream>>>(wd_w1, wd_b1, g1, s1, g2, s2, 1024);
    // decoder layer 2: 16384 x 4096, identity -> xb, dxb
    dual_matvec<false><<<16384, 256, 0, stream>>>(wd_w2, wd_b2, g2, s2, xb, dxb, 4096);
}

// Round 2
// 551.927 us; speedup vs baseline: 1.1280x; 1.1280x over previous
//
#include <hip/hip_runtime.h>
#include <math.h>

typedef float vfloat4 __attribute__((ext_vector_type(4)));

// ---------------------------------------------------------------------------
// Wave-per-row dual GEMV.
//   h_out[row] = f(dot(W[row], v) + b[row])
//   t_out[row] = f'(.) * dot(W[row], t)      (JVP tangent)
// One 64-lane wave per row, in-register butterfly reduce, no LDS/barriers.
// W is single-use -> non-temporal loads; v/t stay hot in L2.
// NCOLS is compile-time so the inner loop fully unrolls (deep MLP).
// ---------------------------------------------------------------------------
template <int NCOLS, bool SIG>
__global__ __launch_bounds__(256) void gemv_dual(
    const float* __restrict__ W, const float* __restrict__ b,
    const float* __restrict__ v, const float* __restrict__ t,
    float* __restrict__ h_out, float* __restrict__ t_out, int nrows)
{
    constexpr int NV = NCOLS / 4;      // float4 per row
    constexpr int ITER = NV / 64;      // per-lane iterations
    const int lane = threadIdx.x & 63;
    const int wave = (int)((blockIdx.x * blockDim.x + threadIdx.x) >> 6);
    const int nw = (int)((gridDim.x * blockDim.x) >> 6);
    const vfloat4* __restrict__ v4 = (const vfloat4*)v;
    const vfloat4* __restrict__ t4 = (const vfloat4*)t;

    for (int row = wave; row < nrows; row += nw) {
        const vfloat4* __restrict__ W4 = (const vfloat4*)(W + (size_t)row * NCOLS);
        float ah = 0.f, at = 0.f;
        #pragma unroll 4
        for (int k = 0; k < ITER; ++k) {
            const int i = lane + 64 * k;
            vfloat4 w = __builtin_nontemporal_load(&W4[i]);
            vfloat4 a = v4[i];
            vfloat4 c = t4[i];
            ah += w.x * a.x + w.y * a.y + w.z * a.z + w.w * a.w;
            at += w.x * c.x + w.y * c.y + w.z * c.z + w.w * c.w;
        }
        #pragma unroll
        for (int off = 32; off; off >>= 1) {
            ah += __shfl_down(ah, off, 64);
            at += __shfl_down(at, off, 64);
        }
        if (lane == 0) {
            ah += b[row];
            if (SIG) {
                float s = 1.f / (1.f + expf(-ah));
                h_out[row] = s;
                t_out[row] = s * (1.f - s) * at;
            } else {
                h_out[row] = ah;
                t_out[row] = at;
            }
        }
    }
}

// ---------------------------------------------------------------------------
// head kernel: single block, 1024 threads (16 waves).
//   z  = W2 @ h2 + b2      dz = W2 @ t2          (16 x 1024, wave per row)
//   theta = sindy_library(z)                      (984)
//   dzb = E_w @ theta + E_b                       (16 x 984, wave per row)
//   g1 = sigmoid(U0 @ z + c0), s1 = sig'*(U0 @ dzb)  (1024 rows, thread/row)
// ---------------------------------------------------------------------------
__global__ __launch_bounds__(1024) void head_kernel(
    const float* __restrict__ W2, const float* __restrict__ b2,
    const float* __restrict__ h2, const float* __restrict__ t2,
    const float* __restrict__ Ew, const float* __restrict__ Eb,
    const float* __restrict__ U0, const float* __restrict__ c0,
    float* __restrict__ out,
    float* __restrict__ g1, float* __restrict__ s1)
{
    __shared__ float z_s[16], dz_s[16], dzb_s[16];
    __shared__ float theta[984];

    const int tid = threadIdx.x;
    const int lane = tid & 63;
    const int r = tid >> 6;            // wave id 0..15

    // ---- z, dz: wave r handles row r of W2 (1024 cols) ----
    {
        const vfloat4* Wr = (const vfloat4*)(W2 + r * 1024);
        const vfloat4* h4 = (const vfloat4*)h2;
        const vfloat4* t4 = (const vfloat4*)t2;
        float ah = 0.f, at = 0.f;
        #pragma unroll
        for (int k = 0; k < 4; ++k) {
            const int i = lane + 64 * k;
            vfloat4 w = Wr[i];
            vfloat4 a = h4[i];
            vfloat4 c = t4[i];
            ah += w.x * a.x + w.y * a.y + w.z * a.z + w.w * a.w;
            at += w.x * c.x + w.y * c.y + w.z * c.z + w.w * c.w;
        }
        #pragma unroll
        for (int off = 32; off; off >>= 1) {
            ah += __shfl_down(ah, off, 64);
            at += __shfl_down(at, off, 64);
        }
        if (lane == 0) {
            z_s[r] = ah + b2[r];
            dz_s[r] = at;
        }
    }
    __syncthreads();

    // ---- sindy library: [1]*16 ++ z ++ quad(136) ++ cub(816) ----
    if (tid < 16) { theta[tid] = 1.0f; theta[16 + tid] = z_s[tid]; }
    for (int t = tid; t < 136; t += 1024) {
        int rem = t, i = 0;
        while (rem >= 16 - i) { rem -= 16 - i; i++; }
        theta[32 + t] = z_s[i] * z_s[i + rem];
    }
    for (int t = tid; t < 816; t += 1024) {
        int rem = t, i = 0;
        for (;;) { int cnt = (16 - i) * (17 - i) >> 1; if (rem < cnt) break; rem -= cnt; i++; }
        int j = i;
        while (rem >= 16 - j) { rem -= 16 - j; j++; }
        theta[168 + t] = z_s[i] * z_s[j] * z_s[j + rem];
    }
    __syncthreads();

    // ---- dzb = E_w @ theta + E_b: wave r handles row r (984 cols) ----
    {
        const vfloat4* Er = (const vfloat4*)(Ew + r * 984);
        const vfloat4* th4 = (const vfloat4*)theta;
        float a = 0.f;
        for (int i = lane; i < 246; i += 64) {     // 984/4 = 246
            vfloat4 w = Er[i];
            vfloat4 x = th4[i];
            a += w.x * x.x + w.y * x.y + w.z * x.z + w.w * x.w;
        }
        #pragma unroll
        for (int off = 32; off; off >>= 1) a += __shfl_down(a, off, 64);
        if (lane == 0) dzb_s[r] = a + Eb[r];
    }
    __syncthreads();

    // ---- outputs z, dz, dzb ----
    if (tid < 16) {
        out[tid]      = z_s[tid];
        out[16 + tid] = dz_s[tid];
        out[32 + tid] = dzb_s[tid];
    }

    // ---- decoder layer 0: 1024 rows, one thread per row ----
    {
        const vfloat4* U4 = (const vfloat4*)(U0 + tid * 16);
        float ah = 0.f, at = 0.f;
        #pragma unroll
        for (int q = 0; q < 4; ++q) {
            vfloat4 w = U4[q];
            ah += w.x * z_s[4*q] + w.y * z_s[4*q+1] + w.z * z_s[4*q+2] + w.w * z_s[4*q+3];
            at += w.x * dzb_s[4*q] + w.y * dzb_s[4*q+1] + w.z * dzb_s[4*q+2] + w.w * dzb_s[4*q+3];
        }
        ah += c0[tid];
        float s = 1.f / (1.f + expf(-ah));
        g1[tid] = s;
        s1[tid] = s * (1.f - s) * at;
    }
}

extern "C" void kernel_launch(void* const* d_in, const int* in_sizes, int n_in,
                              void* d_out, int out_size, void* d_ws, size_t ws_size,
                              hipStream_t stream)
{
    const float* x     = (const float*)d_in[0];
    const float* dx    = (const float*)d_in[1];
    // d_in[2] = ddx: unused by the reference
    const float* we_w0 = (const float*)d_in[3];
    const float* we_b0 = (const float*)d_in[4];
    const float* we_w1 = (const float*)d_in[5];
    const float* we_b1 = (const float*)d_in[6];
    const float* we_w2 = (const float*)d_in[7];
    const float* we_b2 = (const float*)d_in[8];
    const float* wd_w0 = (const float*)d_in[9];
    const float* wd_b0 = (const float*)d_in[10];
    const float* wd_w1 = (const float*)d_in[11];
    const float* wd_b1 = (const float*)d_in[12];
    const float* wd_w2 = (const float*)d_in[13];
    const float* wd_b2 = (const float*)d_in[14];
    const float* E_w   = (const float*)d_in[15];
    const float* E_b   = (const float*)d_in[16];

    float* out = (float*)d_out;   // z[16] dz[16] dzb[16] xb[16384] dxb[16384]
    float* ws  = (float*)d_ws;

    // workspace layout (floats)
    float* h1 = ws;            // 4096
    float* t1 = ws + 4096;     // 4096
    float* h2 = ws + 8192;     // 1024
    float* t2 = ws + 9216;     // 1024
    float* g1 = ws + 10240;    // 1024
    float* s1 = ws + 11264;    // 1024
    float* g2 = ws + 12288;    // 4096
    float* s2 = ws + 16384;    // 4096

    float* xb  = out + 48;
    float* dxb = out + 48 + 16384;

    // encoder layer 0: 4096 rows x 16384 cols, sigmoid (wave per row)
    gemv_dual<16384, true><<<1024, 256, 0, stream>>>(we_w0, we_b0, x, dx, h1, t1, 4096);
    // encoder layer 1: 1024 rows x 4096 cols, sigmoid
    gemv_dual<4096, true><<<256, 256, 0, stream>>>(we_w1, we_b1, h1, t1, h2, t2, 1024);
    // head: z/dz, sindy library, dzb, decoder layer 0
    head_kernel<<<1, 1024, 0, stream>>>(we_w2, we_b2, h2, t2, E_w, E_b,
                                        wd_w0, wd_b0, out, g1, s1);
    // decoder layer 1: 4096 rows x 1024 cols, sigmoid
    gemv_dual<1024, true><<<1024, 256, 0, stream>>>(wd_w1, wd_b1, g1, s1, g2, s2, 4096);
    // decoder layer 2: 16384 rows x 4096 cols, identity -> xb, dxb
    gemv_dual<4096, false><<<4096, 256, 0, stream>>>(wd_w2, wd_b2, g2, s2, xb, dxb, 16384);
}